// Round 22
// baseline (159.723 us; speedup 1.0000x reference)
//
#include <hip/hip_runtime.h>

typedef short bf16x8_t __attribute__((ext_vector_type(8)));
typedef float f32x4_t  __attribute__((ext_vector_type(4)));

#define MFMA16(a,b,c) __builtin_amdgcn_mfma_f32_16x16x32_bf16(a,b,c,0,0,0)

__device__ __forceinline__ unsigned short f2b(float x){
  unsigned u = __float_as_uint(x);
  u += 0x7fffu + ((u >> 16) & 1u);
  return (unsigned short)(u >> 16);
}

__device__ __forceinline__ void bar_lgkm(){
  asm volatile("s_waitcnt lgkmcnt(0)" ::: "memory");
  __builtin_amdgcn_s_barrier();
  __builtin_amdgcn_sched_barrier(0);
}

// ---------------- merged: qs (0..2047) | weights->bf16 (2048..2303) | n_real (2304..2431) | cnt zero (2432) ----------------
__global__ __launch_bounds__(256) void setup_qs(
    const float* __restrict__ context, const float* __restrict__ queries,
    const float* __restrict__ logt, const float* __restrict__ condw,
    const float* __restrict__ condb,
    const float* __restrict__ kw, const float* __restrict__ vw,
    const int* __restrict__ mask,
    unsigned short* __restrict__ qs,
    unsigned short* __restrict__ wktb, unsigned short* __restrict__ wvb,
    int* __restrict__ nreal, int* __restrict__ cnt){
  int bid = blockIdx.x, tid = threadIdx.x;
  if (bid < 2048){
    __shared__ float ctx_l[8 * 64];
    int q   = bid & 31;
    int b0  = (bid >> 5) * 8;
    int qd  = q * 256 + tid;
    float4 cw[16];
    #pragma unroll
    for (int j = 0; j < 16; ++j) cw[j] = *(const float4*)(condw + (size_t)qd * 64 + 4 * j);
    float qbias = queries[qd] + condb[qd];
    float sc = 0.0625f * __expf(-logt[q >> 2]);      // scale * inv_temperature
    ctx_l[tid]       = context[(size_t)b0 * 64 + tid];
    ctx_l[tid + 256] = context[(size_t)b0 * 64 + tid + 256];
    __syncthreads();
    #pragma unroll
    for (int b = 0; b < 8; ++b){
      const float4* cl = (const float4*)(ctx_l + b * 64);
      float acc = 0.f;
      #pragma unroll
      for (int j = 0; j < 16; ++j){
        float4 cv = cl[j]; float4 w4 = cw[j];
        acc += cv.x * w4.x + cv.y * w4.y + cv.z * w4.z + cv.w * w4.w;
      }
      qs[((size_t)(b0 + b) * 32 + q) * 256 + tid] = f2b((qbias + acc) * sc);
    }
  } else if (bid < 2304){
    int i = (bid - 2048) * 256 + tid;              // 0..65535
    int d = i >> 8, e = i & 255;
    wktb[i] = f2b(kw[e * 256 + d]);                // WkT[d][e] (for fused qkp prologue)
    wvb[i]  = f2b(vw[i]);                          // value_w as-is (for fused epilogue)
  } else if (bid < 2432){
    int b = (bid - 2304) * 4 + (tid >> 6), l = tid & 63;
    int s_ = 0;
    #pragma unroll
    for (int j = 0; j < 8; ++j) s_ += mask[(size_t)b * 512 + j * 64 + l];
    #pragma unroll
    for (int k = 1; k < 64; k <<= 1) s_ += __shfl_xor(s_, k);
    if (l == 0) nreal[b] = s_ < 1 ? 1 : (s_ > 512 ? 512 : s_);
  } else {
    cnt[tid] = 0; cnt[tid + 256] = 0;              // per-batch completion counters
  }
}

// ---------------- attention, chunked + last-finisher epilogue. One block per (batch, 256-pos chunk). ----------------
__global__ __launch_bounds__(256, 2) void attn_part(
    const float* __restrict__ keys, const int* __restrict__ nreal,
    const unsigned short* __restrict__ qs, const unsigned short* __restrict__ wkt,
    const unsigned short* __restrict__ wvb,
    float* __restrict__ accw, float* __restrict__ dengw, int* __restrict__ cnt,
    float* __restrict__ out){
  __shared__ unsigned short K[64 * 256];   // bf16 keys, swizzled, 32 KB (reused by epilogue)
  __shared__ unsigned short vT[256 * 64];  // K^T [e][t], swizzled, 32 KB (reused by qkp prologue)
  __shared__ unsigned short Pl[32 * 64];   // P [q][t] bf16, swizzled, 4 KB
  __shared__ float denl[32];
  __shared__ int flag;

  // XCD pair swizzle: 1024 = 8 x 128; both chunks of a batch contiguous (locality heuristic only)
  int lbid = (blockIdx.x & 7) * 128 + (blockIdx.x >> 3);
  int b = lbid >> 1, ch = lbid & 1;
  int n_real = nreal[b];
  int sbase = ch * 256;
  if (sbase >= n_real) return;                 // uniform early-exit (ch=1 only), before any barrier
  bool solo = (n_real <= 256);                 // fast path: ch0 owns the whole batch

  int tid = threadIdx.x, w = tid >> 6, l = tid & 63, h = l >> 4, c = l & 15;
  int qg = w & 1, rp = w >> 1;                 // q-group, row-pair base
  if (tid < 32) denl[tid] = 0.f;

  f32x4_t zero4 = {0.f, 0.f, 0.f, 0.f};

  // identity B-fragments for MFMA-transpose (exact for bf16 inputs)
  bf16x8_t bIe, bIo;
  #pragma unroll
  for (int j = 0; j < 8; ++j){
    bIe[j] = (h == (c >> 3)     && j == (c & 7)) ? (short)0x3F80 : (short)0;
    bIo[j] = (h == 2 + (c >> 3) && j == (c & 7)) ? (short)0x3F80 : (short)0;
  }

  int tv = n_real - sbase;
  int tend = (tv + 63) >> 6; if (tend > 4) tend = 4;

  // stage tile 0 into registers (16 x dwordx4 per lane; rows t = 4j + w, cols 4l..4l+3)
  const float* kptr = keys + ((size_t)b * 512 + sbase + w) * 256 + 4 * l;
  float4 R[16];
  #pragma unroll
  for (int j = 0; j < 16; ++j) R[j] = *(const float4*)(kptr + j * 1024);

  // ---- fused qkp prologue: qf fragments = (qs[b] @ WkT), computed in-block ----
  bf16x8_t qf[8];
  {
    unsigned short* qtmp = vT;           // free until tile-0 transpose (post-BAR1)
    f32x4_t qa[4][2];
    #pragma unroll
    for (int mt = 0; mt < 4; ++mt){ qa[mt][0] = zero4; qa[mt][1] = zero4; }
    #pragma unroll
    for (int kk = 0; kk < 8; ++kk){
      int colk = kk * 32 + 8 * h;
      bf16x8_t B0 = *(const bf16x8_t*)(qs + ((size_t)b * 32 + c) * 256 + colk);
      bf16x8_t B1 = *(const bf16x8_t*)(qs + ((size_t)b * 32 + 16 + c) * 256 + colk);
      #pragma unroll
      for (int mt = 0; mt < 4; ++mt){
        int d = 64 * w + 16 * mt + c;
        bf16x8_t Av = *(const bf16x8_t*)(wkt + (size_t)d * 256 + colk);
        qa[mt][0] = MFMA16(Av, B0, qa[mt][0]);
        qa[mt][1] = MFMA16(Av, B1, qa[mt][1]);
      }
    }
    #pragma unroll
    for (int mt = 0; mt < 4; ++mt)
      #pragma unroll
      for (int qt2 = 0; qt2 < 2; ++qt2)
        #pragma unroll
        for (int i = 0; i < 4; ++i){
          int q = 16 * qt2 + c;
          int d = 64 * w + 16 * mt + 4 * h + i;
          qtmp[q * 256 + (d ^ ((q & 7) << 3))] = f2b(qa[mt][qt2][i]);
        }
    bar_lgkm();                          // qtmp visible (keys loads stay in flight)
    #pragma unroll
    for (int kk = 0; kk < 8; ++kk){
      int q = 16 * qg + c;
      qf[kk] = *(const bf16x8_t*)&qtmp[q * 256 + ((kk * 32 + 8 * h) ^ ((q & 7) << 3))];
    }
  }

  float slope0 = exp2f(-2.0f * (float)((c & 3) + 1));   // head = q&3

  f32x4_t ao[2][4];
  #pragma unroll
  for (int q2 = 0; q2 < 2; ++q2)
    #pragma unroll
    for (int nt = 0; nt < 4; ++nt) ao[q2][nt] = zero4;

  for (int it = 0; it < tend; ++it){
    int s0 = sbase + it * 64;
    // ---- convert R -> K (bf16, swizzled); interleave issue of next tile's loads ----
    const float* knext = kptr + (size_t)(it + 1) * (64 * 256);
    #pragma unroll
    for (int j = 0; j < 16; ++j){
      int row = 4 * j + w;
      int d4 = 4 * l;
      float4 kv = R[j];
      if (it + 1 < tend) R[j] = *(const float4*)(knext + j * 1024);
      uint2 p;
      p.x = (unsigned)f2b(kv.x) | ((unsigned)f2b(kv.y) << 16);
      p.y = (unsigned)f2b(kv.z) | ((unsigned)f2b(kv.w) << 16);
      *(uint2*)&K[row * 256 + (d4 ^ ((row & 7) << 3))] = p;
    }
    bar_lgkm();                          // BAR1: K visible; staging loads stay in flight

    // ---- logits (2 row-groups x own q-group) + K^T for e-range 64w (identity MFMA, streamed) ----
    f32x4_t as_[2];
    as_[0] = zero4; as_[1] = zero4;
    #pragma unroll
    for (int kk = 0; kk < 8; ++kk){
      int colk = kk * 32 + 8 * h;
      {
        int r0_ = 16 * (2 * rp) + c, r1_ = 16 * (2 * rp + 1) + c;
        bf16x8_t A0 = *(const bf16x8_t*)&K[r0_ * 256 + (colk ^ ((r0_ & 7) << 3))];
        bf16x8_t A1 = *(const bf16x8_t*)&K[r1_ * 256 + (colk ^ ((r1_ & 7) << 3))];
        as_[0] = MFMA16(A0, qf[kk], as_[0]);
        as_[1] = MFMA16(A1, qf[kk], as_[1]);
      }
      if ((kk >> 1) == w){               // this wave's e-range: kk = 2w, 2w+1
        int ntb = (kk & 1) << 1;
        int e0 = 64 * w + 16 * ntb + c;
        int e1 = e0 + 16;
        #pragma unroll
        for (int g = 0; g < 4; ++g){
          int rg_ = 16 * g + c;
          bf16x8_t Ag = *(const bf16x8_t*)&K[rg_ * 256 + (colk ^ ((rg_ & 7) << 3))];
          f32x4_t tE = MFMA16(Ag, bIe, zero4);
          f32x4_t tO = MFMA16(Ag, bIo, zero4);
          int t0 = 16 * g + 4 * h;
          uint2 p;
          p.x = (unsigned)f2b(tE[0]) | ((unsigned)f2b(tE[1]) << 16);
          p.y = (unsigned)f2b(tE[2]) | ((unsigned)f2b(tE[3]) << 16);
          *(uint2*)&vT[e0 * 64 + (t0 ^ ((e0 & 7) << 3))] = p;
          p.x = (unsigned)f2b(tO[0]) | ((unsigned)f2b(tO[1]) << 16);
          p.y = (unsigned)f2b(tO[2]) | ((unsigned)f2b(tO[3]) << 16);
          *(uint2*)&vT[e1 * 64 + (t0 ^ ((e1 & 7) << 3))] = p;
        }
      }
    }

    // ---- softmax (fixed-max): P = exp(logit - slope*games_ago), masked -> 0 ----
    {
      float qs_ = 0.f;
      int q = 16 * qg + c;
      #pragma unroll
      for (int g2 = 0; g2 < 2; ++g2){
        int gr = 2 * rp + g2;
        float e_[4];
        #pragma unroll
        for (int i = 0; i < 4; ++i){
          int s = s0 + 16 * gr + 4 * h + i;
          float ga = (float)(n_real - 1 - s);
          bool valid = (s < n_real);
          float v = valid ? __expf(as_[g2][i] - slope0 * ga) : 0.f;
          e_[i] = v; qs_ += v;
        }
        int t0 = 16 * gr + 4 * h;
        uint2 p;
        p.x = (unsigned)f2b(e_[0]) | ((unsigned)f2b(e_[1]) << 16);
        p.y = (unsigned)f2b(e_[2]) | ((unsigned)f2b(e_[3]) << 16);
        *(uint2*)&Pl[q * 64 + (t0 ^ ((q & 7) << 3))] = p;
      }
      float r = qs_ + __shfl_xor(qs_, 16); r += __shfl_xor(r, 32);
      if (l < 16) atomicAdd(&denl[q], r);
    }
    bar_lgkm();                          // BAR2: vT/Pl visible; K consumed

    // ---- PV: ao[q][e] += P[q][t] * K[t][e], t = 64 (2 MFMA k-steps) ----
    #pragma unroll
    for (int ts = 0; ts < 2; ++ts){
      int t0 = 32 * ts + 8 * h;
      bf16x8_t Ap0 = *(const bf16x8_t*)&Pl[c * 64 + (t0 ^ ((c & 7) << 3))];
      bf16x8_t Ap1 = *(const bf16x8_t*)&Pl[(16 + c) * 64 + (t0 ^ (((16 + c) & 7) << 3))];
      #pragma unroll
      for (int nt = 0; nt < 4; ++nt){
        int e = 64 * w + 16 * nt + c;
        bf16x8_t Bv = *(const bf16x8_t*)&vT[e * 64 + (t0 ^ ((e & 7) << 3))];
        ao[0][nt] = MFMA16(Ap0, Bv, ao[0][nt]);
        ao[1][nt] = MFMA16(Ap1, Bv, ao[1][nt]);
      }
    }
  }

  // ---- gather final numerator nv[q2][nt][i] and inverse denominators ----
  float nv[2][4][4];
  if (solo){
    #pragma unroll
    for (int q2 = 0; q2 < 2; ++q2)
      #pragma unroll
      for (int i = 0; i < 4; ++i){
        int q = 16 * q2 + 4 * h + i;
        float invd = 1.f / denl[q];
        #pragma unroll
        for (int nt = 0; nt < 4; ++nt) nv[q2][nt][i] = ao[q2][nt][i] * invd;
      }
  } else {
    // publish this chunk's partials (device-coherent stores), then last-finisher combines
    float* mya = accw + ((size_t)(ch * 512 + b) * 32) * 256;
    #pragma unroll
    for (int q2 = 0; q2 < 2; ++q2)
      #pragma unroll
      for (int nt = 0; nt < 4; ++nt){
        int e = 64 * w + 16 * nt + c;
        #pragma unroll
        for (int i = 0; i < 4; ++i){
          int q = 16 * q2 + 4 * h + i;
          __hip_atomic_store(&mya[q * 256 + e], ao[q2][nt][i],
                             __ATOMIC_RELAXED, __HIP_MEMORY_SCOPE_AGENT);
        }
      }
    if (tid < 32)
      __hip_atomic_store(&dengw[(ch * 512 + b) * 32 + tid], denl[tid],
                         __ATOMIC_RELAXED, __HIP_MEMORY_SCOPE_AGENT);
    __syncthreads();                     // all stores issued+drained (vmcnt 0 at barrier)
    if (tid == 0){
      __threadfence();
      flag = __hip_atomic_fetch_add(&cnt[b], 1, __ATOMIC_ACQ_REL, __HIP_MEMORY_SCOPE_AGENT);
    }
    __syncthreads();
    if (flag == 0) return;               // first finisher: done
    __threadfence();
    if (tid < 32){
      float d0 = __hip_atomic_load(&dengw[b * 32 + tid], __ATOMIC_RELAXED, __HIP_MEMORY_SCOPE_AGENT);
      float d1 = __hip_atomic_load(&dengw[(512 + b) * 32 + tid], __ATOMIC_RELAXED, __HIP_MEMORY_SCOPE_AGENT);
      denl[tid] = d0 + d1;
    }
    __syncthreads();
    const float* a0p = accw + ((size_t)b * 32) * 256;
    const float* a1p = accw + ((size_t)(512 + b) * 32) * 256;
    #pragma unroll
    for (int q2 = 0; q2 < 2; ++q2)
      #pragma unroll
      for (int i = 0; i < 4; ++i){
        int q = 16 * q2 + 4 * h + i;
        float invd = 1.f / denl[q];
        #pragma unroll
        for (int nt = 0; nt < 4; ++nt){
          int e = 64 * w + 16 * nt + c;
          float v0 = __hip_atomic_load(&a0p[q * 256 + e], __ATOMIC_RELAXED, __HIP_MEMORY_SCOPE_AGENT);
          float v1 = __hip_atomic_load(&a1p[q * 256 + e], __ATOMIC_RELAXED, __HIP_MEMORY_SCOPE_AGENT);
          nv[q2][nt][i] = (v0 + v1) * invd;
        }
      }
  }

  // ---- FUSED epilogue: out[q][e'] = sum_e nv[q][e] * value_w[e'][e] ----
  {
    unsigned short* at = K;              // K dead after last tile
    __syncthreads();                     // ensure all waves past K reads (solo path)
    #pragma unroll
    for (int q2 = 0; q2 < 2; ++q2)
      #pragma unroll
      for (int i = 0; i < 4; ++i){
        int q = 16 * q2 + 4 * h + i;
        #pragma unroll
        for (int nt = 0; nt < 4; ++nt){
          int e = 64 * w + 16 * nt + c;
          at[q * 256 + (e ^ ((q & 7) << 3))] = f2b(nv[q2][nt][i]);
        }
      }
    __syncthreads();                     // at visible to all waves

    f32x4_t a2[2][4];
    #pragma unroll
    for (int m = 0; m < 2; ++m)
      #pragma unroll
      for (int nt = 0; nt < 4; ++nt) a2[m][nt] = zero4;
    #pragma unroll
    for (int kk = 0; kk < 8; ++kk){
      bf16x8_t A[2];
      #pragma unroll
      for (int m = 0; m < 2; ++m){
        int row = c + 16 * m;
        A[m] = *(const bf16x8_t*)&at[row * 256 + ((kk * 32 + 8 * h) ^ ((row & 7) << 3))];
      }
      #pragma unroll
      for (int nt = 0; nt < 4; ++nt){
        int ep = 64 * w + 16 * nt + c;
        bf16x8_t Bv = *(const bf16x8_t*)(wvb + (size_t)ep * 256 + kk * 32 + 8 * h);
        #pragma unroll
        for (int m = 0; m < 2; ++m) a2[m][nt] = MFMA16(A[m], Bv, a2[m][nt]);
      }
    }
    #pragma unroll
    for (int m = 0; m < 2; ++m)
      #pragma unroll
      for (int nt = 0; nt < 4; ++nt)
        #pragma unroll
        for (int i = 0; i < 4; ++i){
          int row = 16 * m + 4 * h + i;
          int ep = 64 * w + 16 * nt + c;
          out[((size_t)b * 32 + row) * 256 + ep] = a2[m][nt][i];
        }
  }
}

extern "C" void kernel_launch(void* const* d_in, const int* in_sizes, int n_in,
                              void* d_out, int out_size, void* d_ws, size_t ws_size,
                              hipStream_t stream){
  const float* keys    = (const float*)d_in[0];
  const int*   mask    = (const int*)d_in[1];
  const float* context = (const float*)d_in[2];
  const float* queries = (const float*)d_in[3];
  const float* key_w   = (const float*)d_in[4];
  const float* value_w = (const float*)d_in[5];
  const float* logt    = (const float*)d_in[6];
  const float* cond_w  = (const float*)d_in[7];
  const float* cond_b  = (const float*)d_in[8];
  float* out = (float*)d_out;

  unsigned short* wkt = (unsigned short*)d_ws;           // 65536 bf16
  unsigned short* wvb = wkt + 65536;                     // 65536 bf16
  unsigned short* qs  = wvb + 65536;                     // 16384*256 bf16
  float* accw  = (float*)(qs + (size_t)16384 * 256);     // 2*512*32*256 f32 (33.5 MB)
  float* dengw = accw + (size_t)2 * 512 * 32 * 256;      // 2*512*32 f32
  int*   cnt   = (int*)(dengw + 2 * 512 * 32);           // 512 int
  int*   nreal = cnt + 512;                              // 512 int

  hipLaunchKernelGGL(setup_qs, dim3(2433), dim3(256), 0, stream,
                     context, queries, logt, cond_w, cond_b, key_w, value_w, mask,
                     qs, wkt, wvb, nreal, cnt);
  hipLaunchKernelGGL(attn_part, dim3(1024), dim3(256), 0, stream,
                     keys, nreal, qs, wkt, wvb, accw, dengw, cnt, out);
}

// Round 23
// 81.554 us; speedup vs baseline: 1.9585x; 1.9585x over previous
//
#include <hip/hip_runtime.h>

typedef short bf16x8_t __attribute__((ext_vector_type(8)));
typedef float f32x4_t  __attribute__((ext_vector_type(4)));

#define MFMA16(a,b,c) __builtin_amdgcn_mfma_f32_16x16x32_bf16(a,b,c,0,0,0)

__device__ __forceinline__ unsigned short f2b(float x){
  unsigned u = __float_as_uint(x);
  u += 0x7fffu + ((u >> 16) & 1u);
  return (unsigned short)(u >> 16);
}

__device__ __forceinline__ void bar_lgkm(){
  asm volatile("s_waitcnt lgkmcnt(0)" ::: "memory");
  __builtin_amdgcn_s_barrier();
  __builtin_amdgcn_sched_barrier(0);
}

// ---------------- merged: qs (0..2047) | weights->bf16 (2048..2303) | n_real (2304..2431) ----------------
__global__ __launch_bounds__(256) void setup_qs(
    const float* __restrict__ context, const float* __restrict__ queries,
    const float* __restrict__ logt, const float* __restrict__ condw,
    const float* __restrict__ condb,
    const float* __restrict__ kw, const float* __restrict__ vw,
    const int* __restrict__ mask,
    unsigned short* __restrict__ qs,
    unsigned short* __restrict__ wktb, unsigned short* __restrict__ wvb,
    int* __restrict__ nreal){
  int bid = blockIdx.x, tid = threadIdx.x;
  if (bid < 2048){
    __shared__ float ctx_l[8 * 64];
    int q   = bid & 31;
    int b0  = (bid >> 5) * 8;
    int qd  = q * 256 + tid;
    float4 cw[16];
    #pragma unroll
    for (int j = 0; j < 16; ++j) cw[j] = *(const float4*)(condw + (size_t)qd * 64 + 4 * j);
    float qbias = queries[qd] + condb[qd];
    float sc = 0.0625f * __expf(-logt[q >> 2]);      // scale * inv_temperature
    ctx_l[tid]       = context[(size_t)b0 * 64 + tid];
    ctx_l[tid + 256] = context[(size_t)b0 * 64 + tid + 256];
    __syncthreads();
    #pragma unroll
    for (int b = 0; b < 8; ++b){
      const float4* cl = (const float4*)(ctx_l + b * 64);
      float acc = 0.f;
      #pragma unroll
      for (int j = 0; j < 16; ++j){
        float4 cv = cl[j]; float4 w4 = cw[j];
        acc += cv.x * w4.x + cv.y * w4.y + cv.z * w4.z + cv.w * w4.w;
      }
      qs[((size_t)(b0 + b) * 32 + q) * 256 + tid] = f2b((qbias + acc) * sc);
    }
  } else if (bid < 2304){
    int i = (bid - 2048) * 256 + tid;              // 0..65535
    int d = i >> 8, e = i & 255;
    wktb[i] = f2b(kw[e * 256 + d]);                // WkT[d][e] (for fused qkp prologue)
    wvb[i]  = f2b(vw[i]);                          // value_w as-is (for fused epilogue)
  } else {
    int b = (bid - 2304) * 4 + (tid >> 6), l = tid & 63;
    int s_ = 0;
    #pragma unroll
    for (int j = 0; j < 8; ++j) s_ += mask[(size_t)b * 512 + j * 64 + l];
    #pragma unroll
    for (int k = 1; k < 64; k <<= 1) s_ += __shfl_xor(s_, k);
    if (l == 0) nreal[b] = s_ < 1 ? 1 : (s_ > 512 ? 512 : s_);
  }
}

// ---------------- attention, fully fused: qkp-prologue + tiles + Wv epilogue. One block per batch. ----------------
__global__ __launch_bounds__(256, 2) void attn_part(
    const float* __restrict__ keys, const int* __restrict__ nreal,
    const unsigned short* __restrict__ qs, const unsigned short* __restrict__ wkt,
    const unsigned short* __restrict__ wvb, float* __restrict__ out){
  __shared__ unsigned short K[64 * 256];   // bf16 keys, swizzled, 32 KB (reused by epilogue)
  __shared__ unsigned short vT[256 * 64];  // K^T [e][t], swizzled, 32 KB (reused by qkp prologue)
  __shared__ unsigned short Pl[32 * 64];   // P [q][t] bf16, swizzled, 4 KB
  __shared__ float denl[32];

  // XCD swizzle: 512 = 8 x 64; each XCD owns 64 consecutive batches
  int b = (blockIdx.x & 7) * 64 + (blockIdx.x >> 3);
  int n_real = nreal[b];

  int tid = threadIdx.x, w = tid >> 6, l = tid & 63, h = l >> 4, c = l & 15;
  int qg = w & 1, rp = w >> 1;              // q-group, row-pair base (row-groups 2rp, 2rp+1)
  if (tid < 32) denl[tid] = 0.f;

  f32x4_t zero4 = {0.f, 0.f, 0.f, 0.f};

  // identity B-fragments for MFMA-transpose (exact for bf16 inputs)
  bf16x8_t bIe, bIo;
  #pragma unroll
  for (int j = 0; j < 8; ++j){
    bIe[j] = (h == (c >> 3)     && j == (c & 7)) ? (short)0x3F80 : (short)0;
    bIo[j] = (h == 2 + (c >> 3) && j == (c & 7)) ? (short)0x3F80 : (short)0;
  }

  // stage tile 0 into registers (16 x dwordx4 per lane; rows t = 4j + w, cols 4l..4l+3)
  const float* kptr = keys + ((size_t)b * 512 + w) * 256 + 4 * l;
  float4 R[16];
  #pragma unroll
  for (int j = 0; j < 16; ++j) R[j] = *(const float4*)(kptr + j * 1024);

  // ---- fused qkp prologue: qf fragments = (qs[b] @ WkT), computed in-block ----
  // D = WkT-rows (m=d) x qs (n=q): lane c -> q, regs -> d. Fixup d-axis via LDS (vT reused).
  bf16x8_t qf[8];
  {
    unsigned short* qtmp = vT;           // free until tile-0 transpose (post-BAR1)
    f32x4_t qa[4][2];
    #pragma unroll
    for (int mt = 0; mt < 4; ++mt){ qa[mt][0] = zero4; qa[mt][1] = zero4; }
    #pragma unroll
    for (int kk = 0; kk < 8; ++kk){
      int colk = kk * 32 + 8 * h;
      bf16x8_t B0 = *(const bf16x8_t*)(qs + ((size_t)b * 32 + c) * 256 + colk);
      bf16x8_t B1 = *(const bf16x8_t*)(qs + ((size_t)b * 32 + 16 + c) * 256 + colk);
      #pragma unroll
      for (int mt = 0; mt < 4; ++mt){
        int d = 64 * w + 16 * mt + c;
        bf16x8_t Av = *(const bf16x8_t*)(wkt + (size_t)d * 256 + colk);
        qa[mt][0] = MFMA16(Av, B0, qa[mt][0]);
        qa[mt][1] = MFMA16(Av, B1, qa[mt][1]);
      }
    }
    #pragma unroll
    for (int mt = 0; mt < 4; ++mt)
      #pragma unroll
      for (int qt2 = 0; qt2 < 2; ++qt2)
        #pragma unroll
        for (int i = 0; i < 4; ++i){
          int q = 16 * qt2 + c;
          int d = 64 * w + 16 * mt + 4 * h + i;
          qtmp[q * 256 + (d ^ ((q & 7) << 3))] = f2b(qa[mt][qt2][i]);
        }
    bar_lgkm();                          // qtmp visible to all waves (keys loads stay in flight)
    #pragma unroll
    for (int kk = 0; kk < 8; ++kk){
      int q = 16 * qg + c;
      qf[kk] = *(const bf16x8_t*)&qtmp[q * 256 + ((kk * 32 + 8 * h) ^ ((q & 7) << 3))];
    }
    // qf ds_reads complete before each wave's BAR1 arrival (lgkmcnt(0)); vT writes are post-BAR1.
  }

  float slope0 = exp2f(-2.0f * (float)((c & 3) + 1));   // head = q&3

  f32x4_t ao[2][4];
  #pragma unroll
  for (int q2 = 0; q2 < 2; ++q2)
    #pragma unroll
    for (int nt = 0; nt < 4; ++nt) ao[q2][nt] = zero4;

  int tend = (n_real + 63) >> 6;            // 1..8

  for (int it = 0; it < tend; ++it){
    int s0 = it * 64;
    // ---- convert R -> K (bf16, swizzled); interleave issue of next tile's loads ----
    const float* knext = kptr + (size_t)(it + 1) * (64 * 256);
    #pragma unroll
    for (int j = 0; j < 16; ++j){
      int row = 4 * j + w;
      int d4 = 4 * l;
      float4 kv = R[j];
      if (it + 1 < tend) R[j] = *(const float4*)(knext + j * 1024);
      uint2 p;
      p.x = (unsigned)f2b(kv.x) | ((unsigned)f2b(kv.y) << 16);
      p.y = (unsigned)f2b(kv.z) | ((unsigned)f2b(kv.w) << 16);
      *(uint2*)&K[row * 256 + (d4 ^ ((row & 7) << 3))] = p;
    }
    bar_lgkm();                          // BAR1: K visible; staging loads stay in flight

    // ---- logits (2 row-groups x own q-group) + K^T for e-range 64w (identity MFMA, streamed) ----
    f32x4_t as_[2];
    as_[0] = zero4; as_[1] = zero4;
    #pragma unroll
    for (int kk = 0; kk < 8; ++kk){
      int colk = kk * 32 + 8 * h;
      {
        int r0_ = 16 * (2 * rp) + c, r1_ = 16 * (2 * rp + 1) + c;
        bf16x8_t A0 = *(const bf16x8_t*)&K[r0_ * 256 + (colk ^ ((r0_ & 7) << 3))];
        bf16x8_t A1 = *(const bf16x8_t*)&K[r1_ * 256 + (colk ^ ((r1_ & 7) << 3))];
        as_[0] = MFMA16(A0, qf[kk], as_[0]);
        as_[1] = MFMA16(A1, qf[kk], as_[1]);
      }
      if ((kk >> 1) == w){               // this wave's e-range: kk = 2w, 2w+1
        int ntb = (kk & 1) << 1;
        int e0 = 64 * w + 16 * ntb + c;
        int e1 = e0 + 16;
        #pragma unroll
        for (int g = 0; g < 4; ++g){     // all 4 row-groups -> t = 16g + 4h..
          int rg_ = 16 * g + c;
          bf16x8_t Ag = *(const bf16x8_t*)&K[rg_ * 256 + (colk ^ ((rg_ & 7) << 3))];
          f32x4_t tE = MFMA16(Ag, bIe, zero4);
          f32x4_t tO = MFMA16(Ag, bIo, zero4);
          int t0 = 16 * g + 4 * h;
          uint2 p;
          p.x = (unsigned)f2b(tE[0]) | ((unsigned)f2b(tE[1]) << 16);
          p.y = (unsigned)f2b(tE[2]) | ((unsigned)f2b(tE[3]) << 16);
          *(uint2*)&vT[e0 * 64 + (t0 ^ ((e0 & 7) << 3))] = p;
          p.x = (unsigned)f2b(tO[0]) | ((unsigned)f2b(tO[1]) << 16);
          p.y = (unsigned)f2b(tO[2]) | ((unsigned)f2b(tO[3]) << 16);
          *(uint2*)&vT[e1 * 64 + (t0 ^ ((e1 & 7) << 3))] = p;
        }
      }
    }

    // ---- softmax (fixed-max): P = exp(logit - slope*games_ago), masked -> 0 ----
    {
      float qs_ = 0.f;
      int q = 16 * qg + c;
      #pragma unroll
      for (int g2 = 0; g2 < 2; ++g2){
        int gr = 2 * rp + g2;
        float e_[4];
        #pragma unroll
        for (int i = 0; i < 4; ++i){
          int s = s0 + 16 * gr + 4 * h + i;
          float ga = (float)(n_real - 1 - s);
          bool valid = (s < n_real);
          float v = valid ? __expf(as_[g2][i] - slope0 * ga) : 0.f;
          e_[i] = v; qs_ += v;
        }
        int t0 = 16 * gr + 4 * h;
        uint2 p;
        p.x = (unsigned)f2b(e_[0]) | ((unsigned)f2b(e_[1]) << 16);
        p.y = (unsigned)f2b(e_[2]) | ((unsigned)f2b(e_[3]) << 16);
        *(uint2*)&Pl[q * 64 + (t0 ^ ((q & 7) << 3))] = p;
      }
      float r = qs_ + __shfl_xor(qs_, 16); r += __shfl_xor(r, 32);
      if (l < 16) atomicAdd(&denl[q], r);
    }
    bar_lgkm();                          // BAR2: vT/Pl visible; K consumed

    // ---- PV: ao[q][e] += P[q][t] * K[t][e], t = 64 (2 MFMA k-steps) ----
    #pragma unroll
    for (int ts = 0; ts < 2; ++ts){
      int t0 = 32 * ts + 8 * h;
      bf16x8_t Ap0 = *(const bf16x8_t*)&Pl[c * 64 + (t0 ^ ((c & 7) << 3))];
      bf16x8_t Ap1 = *(const bf16x8_t*)&Pl[(16 + c) * 64 + (t0 ^ (((16 + c) & 7) << 3))];
      #pragma unroll
      for (int nt = 0; nt < 4; ++nt){
        int e = 64 * w + 16 * nt + c;
        bf16x8_t Bv = *(const bf16x8_t*)&vT[e * 64 + (t0 ^ ((e & 7) << 3))];
        ao[0][nt] = MFMA16(Ap0, Bv, ao[0][nt]);
        ao[1][nt] = MFMA16(Ap1, Bv, ao[1][nt]);
      }
    }
  }

  // ---- FUSED epilogue: out[q][e'] = sum_e (num[q][e]/den[q]) * value_w[e'][e] ----
  {
    unsigned short* at = K;              // K dead after last tile
    #pragma unroll
    for (int q2 = 0; q2 < 2; ++q2)
      #pragma unroll
      for (int i = 0; i < 4; ++i){
        int q = 16 * q2 + 4 * h + i;
        float invd = 1.f / denl[q];
        #pragma unroll
        for (int nt = 0; nt < 4; ++nt){
          int e = 64 * w + 16 * nt + c;
          at[q * 256 + (e ^ ((q & 7) << 3))] = f2b(ao[q2][nt][i] * invd);
        }
      }
    __syncthreads();                     // at visible to all waves

    f32x4_t a2[2][4];
    #pragma unroll
    for (int m = 0; m < 2; ++m)
      #pragma unroll
      for (int nt = 0; nt < 4; ++nt) a2[m][nt] = zero4;
    #pragma unroll
    for (int kk = 0; kk < 8; ++kk){
      bf16x8_t A[2];
      #pragma unroll
      for (int m = 0; m < 2; ++m){
        int row = c + 16 * m;
        A[m] = *(const bf16x8_t*)&at[row * 256 + ((kk * 32 + 8 * h) ^ ((row & 7) << 3))];
      }
      #pragma unroll
      for (int nt = 0; nt < 4; ++nt){
        int ep = 64 * w + 16 * nt + c;
        bf16x8_t Bv = *(const bf16x8_t*)(wvb + (size_t)ep * 256 + kk * 32 + 8 * h);
        #pragma unroll
        for (int m = 0; m < 2; ++m) a2[m][nt] = MFMA16(A[m], Bv, a2[m][nt]);
      }
    }
    #pragma unroll
    for (int m = 0; m < 2; ++m)
      #pragma unroll
      for (int nt = 0; nt < 4; ++nt)
        #pragma unroll
        for (int i = 0; i < 4; ++i){
          int row = 16 * m + 4 * h + i;
          int ep = 64 * w + 16 * nt + c;
          out[((size_t)b * 32 + row) * 256 + ep] = a2[m][nt][i];
        }
  }
}

extern "C" void kernel_launch(void* const* d_in, const int* in_sizes, int n_in,
                              void* d_out, int out_size, void* d_ws, size_t ws_size,
                              hipStream_t stream){
  const float* keys    = (const float*)d_in[0];
  const int*   mask    = (const int*)d_in[1];
  const float* context = (const float*)d_in[2];
  const float* queries = (const float*)d_in[3];
  const float* key_w   = (const float*)d_in[4];
  const float* value_w = (const float*)d_in[5];
  const float* logt    = (const float*)d_in[6];
  const float* cond_w  = (const float*)d_in[7];
  const float* cond_b  = (const float*)d_in[8];
  float* out = (float*)d_out;

  unsigned short* wkt = (unsigned short*)d_ws;           // 65536 bf16
  unsigned short* wvb = wkt + 65536;                     // 65536 bf16
  unsigned short* qs  = wvb + 65536;                     // 16384*256 bf16
  int*   nreal = (int*)(qs + (size_t)16384 * 256);       // 512 int

  hipLaunchKernelGGL(setup_qs, dim3(2432), dim3(256), 0, stream,
                     context, queries, logt, cond_w, cond_b, key_w, value_w, mask,
                     qs, wkt, wvb, nreal);
  hipLaunchKernelGGL(attn_part, dim3(512), dim3(256), 0, stream, keys, nreal, qs, wkt, wvb, out);
}